// Round 3
// baseline (301.614 us; speedup 1.0000x reference)
//
#include <hip/hip_runtime.h>
#include <hip/hip_bf16.h>
#include <cmath>

// Problem constants (from reference)
#define BATCH   2
#define NQ      5376
#define NV      5376
#define CDIM    256
#define HEADS   8
#define HD      32
#define LEVELS  3
#define POINTS  4
#define TP      96      // HEADS*LEVELS*POINTS
#define MROWS   (BATCH*NQ)   // 10752
#define NOFF    (TP*2)       // 192
#define NQA     (NOFF+TP)    // 288 merged off||a columns
#define NQAP    320          // padded rows of merged qa weight (zeros 288..319)

typedef __attribute__((ext_vector_type(8))) short bf16x8;
typedef __attribute__((ext_vector_type(4))) float f32x4;
typedef unsigned short u16;
typedef unsigned int   u32;

#define AS1 __attribute__((address_space(1)))
#define AS3 __attribute__((address_space(3)))

__device__ __forceinline__ void g2lds16(const void* g, void* l) {
    // async global->LDS, 16B per lane; LDS dest = wave-uniform base + lane*16
    __builtin_amdgcn_global_load_lds((const AS1 void*)g, (AS3 void*)l, 16, 0, 0);
}

__device__ __forceinline__ u16 bf_of(float f) {
    union { __hip_bfloat16 h; u16 s; } u;
    u.h = __float2bfloat16(f);
    return u.s;
}
__device__ __forceinline__ float bf_back(u16 s) {
    return __uint_as_float((u32)s << 16);
}

__device__ __forceinline__ ushort4 cvt_hi(float4 v) {
    ushort4 h;
    h.x = bf_of(v.x); h.y = bf_of(v.y); h.z = bf_of(v.z); h.w = bf_of(v.w);
    return h;
}
__device__ __forceinline__ ushort4 cvt_lo(float4 v, ushort4 h) {
    ushort4 l;
    l.x = bf_of(v.x - bf_back(h.x));
    l.y = bf_of(v.y - bf_back(h.y));
    l.z = bf_of(v.z - bf_back(h.z));
    l.w = bf_of(v.w - bf_back(h.w));
    return l;
}

// ---------------------------------------------------------------------------
// Device-scope grid barrier (plain launch, co-residency guaranteed by the
// host-side occupancy clamp). Release fence writes back L2 (cross-XCD
// visibility), acquire fence invalidates it — same semantics as a kernel
// boundary. Counters zeroed per replay by a hipMemsetAsync node.
// ---------------------------------------------------------------------------
__device__ __forceinline__ void grid_barrier(unsigned* bar, int nb) {
    __syncthreads();
    if (threadIdx.x == 0) {
        __builtin_amdgcn_fence(__ATOMIC_RELEASE, "agent");   // L2 writeback
        atomicAdd(bar, 1u);
        while (__hip_atomic_load(bar, __ATOMIC_RELAXED,
                                 __HIP_MEMORY_SCOPE_AGENT) < (unsigned)nb)
            __builtin_amdgcn_s_sleep(2);
        __builtin_amdgcn_fence(__ATOMIC_ACQUIRE, "agent");   // L2 invalidate
    }
    __syncthreads();
}

// ---------------------------------------------------------------------------
// Phase 0: one-shot conversion pass (~40 MB).
//   value -> val_hi, val_lo ; query -> q_hi ; Wv/Woff||Wa(+pad)/Wo -> bf16
// NOTE: no `return`s — this runs inside the fused kernel.
// ---------------------------------------------------------------------------
#define NVAL8  344064   // 2*5376*256/8
#define NQRY8  344064
#define NWV8   8192     // 256*256/8
#define NWOFF8 6144     // 192*256/8
#define NWA8   3072     // 96*256/8
#define NWO8   8192
#define NPAD8  1024     // 32*256/8
#define PREP_ITEMS (NVAL8+NQRY8+NWV8+NWOFF8+NWA8+NWO8+NPAD8)  // 714752
#define PREP_BLOCKS (PREP_ITEMS/256)   // 2792

__device__ __forceinline__ void prep_item(int r,
    const float* __restrict__ value, const float* __restrict__ query,
    const float* __restrict__ Wv, const float* __restrict__ Woff,
    const float* __restrict__ Wa, const float* __restrict__ Wo,
    u16* __restrict__ val_hi, u16* __restrict__ val_lo,
    u16* __restrict__ q_hi, u16* __restrict__ wv_h,
    u16* __restrict__ wqa_h, u16* __restrict__ wo_h)
{
    if (r < NVAL8) {
        const float4 a0 = *reinterpret_cast<const float4*>(value + (size_t)r * 8);
        const float4 a1 = *reinterpret_cast<const float4*>(value + (size_t)r * 8 + 4);
        const ushort4 h0 = cvt_hi(a0), h1 = cvt_hi(a1);
        *reinterpret_cast<ushort4*>(val_hi + (size_t)r * 8)     = h0;
        *reinterpret_cast<ushort4*>(val_hi + (size_t)r * 8 + 4) = h1;
        *reinterpret_cast<ushort4*>(val_lo + (size_t)r * 8)     = cvt_lo(a0, h0);
        *reinterpret_cast<ushort4*>(val_lo + (size_t)r * 8 + 4) = cvt_lo(a1, h1);
    } else {
        r -= NVAL8;
        if (r < NQRY8) {
            const float4 a0 = *reinterpret_cast<const float4*>(query + (size_t)r * 8);
            const float4 a1 = *reinterpret_cast<const float4*>(query + (size_t)r * 8 + 4);
            *reinterpret_cast<ushort4*>(q_hi + (size_t)r * 8)     = cvt_hi(a0);
            *reinterpret_cast<ushort4*>(q_hi + (size_t)r * 8 + 4) = cvt_hi(a1);
        } else {
            r -= NQRY8;
            if (r < NWV8) {
                const float4 a0 = *reinterpret_cast<const float4*>(Wv + (size_t)r * 8);
                const float4 a1 = *reinterpret_cast<const float4*>(Wv + (size_t)r * 8 + 4);
                *reinterpret_cast<ushort4*>(wv_h + (size_t)r * 8)     = cvt_hi(a0);
                *reinterpret_cast<ushort4*>(wv_h + (size_t)r * 8 + 4) = cvt_hi(a1);
            } else {
                r -= NWV8;
                if (r < NWOFF8) {
                    const float4 a0 = *reinterpret_cast<const float4*>(Woff + (size_t)r * 8);
                    const float4 a1 = *reinterpret_cast<const float4*>(Woff + (size_t)r * 8 + 4);
                    *reinterpret_cast<ushort4*>(wqa_h + (size_t)r * 8)     = cvt_hi(a0);
                    *reinterpret_cast<ushort4*>(wqa_h + (size_t)r * 8 + 4) = cvt_hi(a1);
                } else {
                    r -= NWOFF8;
                    if (r < NWA8) {
                        const float4 a0 = *reinterpret_cast<const float4*>(Wa + (size_t)r * 8);
                        const float4 a1 = *reinterpret_cast<const float4*>(Wa + (size_t)r * 8 + 4);
                        u16* dst = wqa_h + (size_t)NOFF * CDIM;
                        *reinterpret_cast<ushort4*>(dst + (size_t)r * 8)     = cvt_hi(a0);
                        *reinterpret_cast<ushort4*>(dst + (size_t)r * 8 + 4) = cvt_hi(a1);
                    } else {
                        r -= NWA8;
                        if (r < NWO8) {
                            const float4 a0 = *reinterpret_cast<const float4*>(Wo + (size_t)r * 8);
                            const float4 a1 = *reinterpret_cast<const float4*>(Wo + (size_t)r * 8 + 4);
                            *reinterpret_cast<ushort4*>(wo_h + (size_t)r * 8)     = cvt_hi(a0);
                            *reinterpret_cast<ushort4*>(wo_h + (size_t)r * 8 + 4) = cvt_hi(a1);
                        } else {
                            r -= NWO8;
                            const ushort4 z = {0, 0, 0, 0};
                            u16* dst = wqa_h + (size_t)NQA * CDIM;
                            *reinterpret_cast<ushort4*>(dst + (size_t)r * 8)     = z;
                            *reinterpret_cast<ushort4*>(dst + (size_t)r * 8 + 4) = z;
                        }
                    }
                }
            }
        }
    }
}

__device__ __forceinline__ void phase_prep(int bid, int nb,
    const float* value, const float* query, const float* Wv,
    const float* Woff, const float* Wa, const float* Wo,
    u16* val_hi, u16* val_lo, u16* q_hi,
    u16* wv_h, u16* wqa_h, u16* wo_h)
{
    for (int r = bid * 256 + (int)threadIdx.x; r < PREP_ITEMS; r += nb * 256)
        prep_item(r, value, query, Wv, Woff, Wa, Wo,
                  val_hi, val_lo, q_hi, wv_h, wqa_h, wo_h);
}

// ---------------------------------------------------------------------------
// Phase 1: v-GEMM (hi+lo split) + qa-GEMM, 64x64x32 tiles, pure bf16,
// global_load_lds staging, 2-phase dbuf. Block-stride over 1512 tiles.
// ---------------------------------------------------------------------------
#define GBM 64
#define GBN 64
#define GBK 32
#define VBLOCKS (168 * 4)               // 672 v-path tiles
#define K1_BLOCKS (VBLOCKS + 168 * 5)   // 1512

__device__ __forceinline__ void phase_vqa(char* smem, int bid, int nb,
    const u16* __restrict__ val_hi, const u16* __restrict__ val_lo,
    const u16* __restrict__ q_hi,
    const u16* __restrict__ wv_h, const u16* __restrict__ wqa_h,
    const float* __restrict__ bv, const float* __restrict__ boff,
    const float* __restrict__ ba,
    u16* __restrict__ vOut, u16* __restrict__ offOut, u16* __restrict__ aOut)
{
    u16 (*sAh)[GBM * GBK] = reinterpret_cast<u16(*)[GBM * GBK]>(smem);
    u16 (*sAl)[GBM * GBK] = reinterpret_cast<u16(*)[GBM * GBK]>(smem + 8192);
    u16 (*sBh)[GBM * GBK] = reinterpret_cast<u16(*)[GBM * GBK]>(smem + 16384);

    const int tid  = threadIdx.x;
    const int lane = tid & 63;
    const int wave = tid >> 6;
    const int wr   = wave & 1;
    const int wc   = wave >> 1;
    const int qm   = lane & 15;
    const int quad = lane >> 4;
    const int arow = (wave << 4) + (lane >> 2);
    const int ak   = (lane & 3) * 8;

    for (int t = bid; t < K1_BLOCKS; t += nb) {
        const bool vpath = t < VBLOCKS;
        int m0, n0;
        if (vpath) { m0 = (t >> 2) * GBM;           n0 = (t & 3) * GBM; }
        else       { const int b2 = t - VBLOCKS;
                     m0 = (b2 / 5) * GBM;           n0 = (b2 % 5) * GBM; }

        const u16* Asrc_h = (vpath ? val_hi : q_hi) + (size_t)(m0 + arow) * CDIM + ak;
        const u16* Asrc_l = val_lo + (size_t)(m0 + arow) * CDIM + ak;   // vpath only
        const u16* Bsrc   = (vpath ? wv_h : wqa_h) + (size_t)(n0 + arow) * CDIM + ak;

        f32x4 acc[2][2];
        #pragma unroll
        for (int i = 0; i < 2; ++i)
            #pragma unroll
            for (int j = 0; j < 2; ++j)
                acc[i][j] = (f32x4){0.f, 0.f, 0.f, 0.f};

        // prologue: stage tile 0
        g2lds16(Asrc_h, &sAh[0][wave * 512]);
        if (vpath) g2lds16(Asrc_l, &sAl[0][wave * 512]);
        g2lds16(Bsrc, &sBh[0][wave * 512]);
        __syncthreads();

        int cur = 0;
        for (int k0 = 0; k0 < CDIM; k0 += GBK) {
            if (k0 + GBK < CDIM) {
                g2lds16(Asrc_h + k0 + GBK, &sAh[cur ^ 1][wave * 512]);
                if (vpath) g2lds16(Asrc_l + k0 + GBK, &sAl[cur ^ 1][wave * 512]);
                g2lds16(Bsrc + k0 + GBK, &sBh[cur ^ 1][wave * 512]);
            }

            bf16x8 fah[2], fal[2], fbh[2];
            #pragma unroll
            for (int x = 0; x < 2; ++x) {
                const int rm = wr * 32 + x * 16 + qm;
                const int rn = wc * 32 + x * 16 + qm;
                fah[x] = *reinterpret_cast<const bf16x8*>(&sAh[cur][rm * GBK + quad * 8]);
                fbh[x] = *reinterpret_cast<const bf16x8*>(&sBh[cur][rn * GBK + quad * 8]);
                if (vpath)
                    fal[x] = *reinterpret_cast<const bf16x8*>(&sAl[cur][rm * GBK + quad * 8]);
            }
            #pragma unroll
            for (int mi = 0; mi < 2; ++mi)
                #pragma unroll
                for (int ni = 0; ni < 2; ++ni) {
                    acc[mi][ni] = __builtin_amdgcn_mfma_f32_16x16x32_bf16(
                        fah[mi], fbh[ni], acc[mi][ni], 0, 0, 0);
                    if (vpath)
                        acc[mi][ni] = __builtin_amdgcn_mfma_f32_16x16x32_bf16(
                            fal[mi], fbh[ni], acc[mi][ni], 0, 0, 0);
                }
            __syncthreads();
            cur ^= 1;
        }

        // epilogue: C/D layout col = lane&15 (n), row = quad*4 + reg (m)
        #pragma unroll
        for (int mi = 0; mi < 2; ++mi) {
            #pragma unroll
            for (int ni = 0; ni < 2; ++ni) {
                const int n = n0 + wc * 32 + ni * 16 + qm;
                if (vpath) {
                    const float bn = bv[n];
                    #pragma unroll
                    for (int r = 0; r < 4; ++r) {
                        const int m = m0 + wr * 32 + mi * 16 + quad * 4 + r;
                        const float val = acc[mi][ni][r] + bn;
                        const int b = m / NV, rr = m - b * NV;
                        const int h = n >> 5, c = n & 31;
                        vOut[(((size_t)b * HEADS + h) * NV + rr) * HD + c] = bf_of(val);
                    }
                } else {
                    if (n < NQA) {
                        const float bn = (n < NOFF) ? boff[n] : ba[n - NOFF];
                        #pragma unroll
                        for (int r = 0; r < 4; ++r) {
                            const int m = m0 + wr * 32 + mi * 16 + quad * 4 + r;
                            const float val = acc[mi][ni][r] + bn;
                            if (n < NOFF)
                                offOut[(size_t)m * NOFF + n] = bf_of(val);
                            else
                                aOut[(size_t)m * TP + (n - NOFF)] = bf_of(val);
                        }
                    }
                }
            }
        }
    }
}

// ---------------------------------------------------------------------------
// Phase 2: MSDA core. 4 queries per group, 64 threads per query.
// Block-stride over 2688 groups; leading __syncthreads protects LDS reuse.
// ---------------------------------------------------------------------------
__device__ __forceinline__ void phase_msda(char* smem, int bid, int nb,
    const u16* __restrict__ off, const u16* __restrict__ alog,
    const float* __restrict__ refp, const u16* __restrict__ v,
    u16* __restrict__ t_hi)
{
    float (*s_w)[TP]      = reinterpret_cast<float(*)[TP]>(smem);          // 1536 B
    int   (*s_idx)[TP][4] = reinterpret_cast<int(*)[TP][4]>(smem + 1536);  // 6144 B
    float (*s_twt)[TP][4] = reinterpret_cast<float(*)[TP][4]>(smem + 7680);// 6144 B

    const int tid = threadIdx.x;

    for (int g0 = bid; g0 < MROWS / 4; g0 += nb) {
        __syncthreads();   // prior iteration's gather reads done
        const int bq0 = g0 * 4;

        // logits for 4 queries (384 values)
        #pragma unroll
        for (int base = 0; base < 4 * TP; base += 256) {
            const int idx = base + tid;
            if (idx < 4 * TP) {
                const int q = idx / TP, j = idx - q * TP;
                s_w[q][j] = bf_back(alog[(size_t)(bq0 + q) * TP + j]);
            }
        }
        __syncthreads();

        // 32 softmaxes (4 queries x 8 heads)
        if (tid < 32) {
            const int q = tid >> 3, h = tid & 7;
            float mx = -1e30f;
            #pragma unroll
            for (int i = 0; i < 12; ++i) mx = fmaxf(mx, s_w[q][h * 12 + i]);
            float e[12];
            float sum = 0.f;
            #pragma unroll
            for (int i = 0; i < 12; ++i) {
                e[i] = expf(s_w[q][h * 12 + i] - mx);
                sum += e[i];
            }
            const float inv = 1.f / sum;
            #pragma unroll
            for (int i = 0; i < 12; ++i) s_w[q][h * 12 + i] = e[i] * inv;
        }
        __syncthreads();

        // taps for 4 queries (384 taps)
        #pragma unroll
        for (int base = 0; base < 4 * TP; base += 256) {
            const int idx = base + tid;
            if (idx < 4 * TP) {
                const int q = idx / TP, j = idx - q * TP;
                const int bq = bq0 + q;
                const int jj = j % 12;
                const int l  = jj >> 2;
                const int Wl    = (l == 0) ? 64 : (l == 1) ? 32 : 16;
                const int start = (l == 0) ? 0 : (l == 1) ? 4096 : 5120;

                const float refx = refp[(size_t)bq * 2 + 0];
                const float refy = refp[(size_t)bq * 2 + 1];
                const float ox = bf_back(off[(size_t)bq * NOFF + j * 2 + 0]);
                const float oy = bf_back(off[(size_t)bq * NOFF + j * 2 + 1]);
                const float lx = fminf(fmaxf(refx + ox, 0.f), 1.f) * (float)Wl - 0.5f;
                const float ly = fminf(fmaxf(refy + oy, 0.f), 1.f) * (float)Wl - 0.5f;
                const float fx0 = floorf(lx), fy0 = floorf(ly);
                const int   x0  = (int)fx0,   y0  = (int)fy0;
                const float wx1 = lx - fx0,   wy1 = ly - fy0;
                const float wx0 = 1.f - wx1,  wy0 = 1.f - wy1;
                const float aw  = s_w[q][j];

                #pragma unroll
                for (int k = 0; k < 4; ++k) {
                    const int dx = k & 1, dy = k >> 1;
                    const int xi = x0 + dx, yi = y0 + dy;
                    const bool ok = (xi >= 0) & (xi < Wl) & (yi >= 0) & (yi < Wl);
                    const int xc = min(max(xi, 0), Wl - 1);
                    const int yc = min(max(yi, 0), Wl - 1);
                    s_idx[q][j][k] = (start + yc * Wl + xc) * (HD * 2);  // 64 B rows
                    const float wxy = (dx ? wx1 : wx0) * (dy ? wy1 : wy0);
                    s_twt[q][j][k] = ok ? aw * wxy : 0.f;
                }
            }
        }
        __syncthreads();

        // gather: 64 threads per query
        const int qsel = tid >> 6;
        const int ht   = tid & 63;
        const int h    = ht >> 3;
        const int sub  = ht & 7;
        const int oct  = sub & 3;
        const int rep  = sub >> 2;
        const int bq   = bq0 + qsel;
        const int b    = bq / NQ;
        const char* vb = (const char*)v + (((size_t)b * HEADS + h) * NV) * (HD * 2) + oct * 16;

        float acc[8] = {};
        #pragma unroll
        for (int g = 0; g < 3; ++g) {
            uint4 raw[8];
            float wt[8];
            #pragma unroll
            for (int pp = 0; pp < 2; ++pp) {
                const int j = h * 12 + rep * 6 + g * 2 + pp;
                const int4   ix = *reinterpret_cast<const int4*>(&s_idx[qsel][j][0]);
                const float4 tw = *reinterpret_cast<const float4*>(&s_twt[qsel][j][0]);
                raw[pp * 4 + 0] = *reinterpret_cast<const uint4*>(vb + ix.x);
                raw[pp * 4 + 1] = *reinterpret_cast<const uint4*>(vb + ix.y);
                raw[pp * 4 + 2] = *reinterpret_cast<const uint4*>(vb + ix.z);
                raw[pp * 4 + 3] = *reinterpret_cast<const uint4*>(vb + ix.w);
                wt[pp * 4 + 0] = tw.x; wt[pp * 4 + 1] = tw.y;
                wt[pp * 4 + 2] = tw.z; wt[pp * 4 + 3] = tw.w;
            }
            #pragma unroll
            for (int k = 0; k < 8; ++k) {
                acc[0] += wt[k] * __uint_as_float(raw[k].x << 16);
                acc[1] += wt[k] * __uint_as_float(raw[k].x & 0xffff0000u);
                acc[2] += wt[k] * __uint_as_float(raw[k].y << 16);
                acc[3] += wt[k] * __uint_as_float(raw[k].y & 0xffff0000u);
                acc[4] += wt[k] * __uint_as_float(raw[k].z << 16);
                acc[5] += wt[k] * __uint_as_float(raw[k].z & 0xffff0000u);
                acc[6] += wt[k] * __uint_as_float(raw[k].w << 16);
                acc[7] += wt[k] * __uint_as_float(raw[k].w & 0xffff0000u);
            }
        }

        #pragma unroll
        for (int c = 0; c < 8; ++c)
            acc[c] += __shfl_xor(acc[c], 4);

        if (rep == 0) {
            uint4 o;
            o.x = (u32)bf_of(acc[0]) | ((u32)bf_of(acc[1]) << 16);
            o.y = (u32)bf_of(acc[2]) | ((u32)bf_of(acc[3]) << 16);
            o.z = (u32)bf_of(acc[4]) | ((u32)bf_of(acc[5]) << 16);
            o.w = (u32)bf_of(acc[6]) | ((u32)bf_of(acc[7]) << 16);
            const size_t base = (size_t)bq * CDIM + h * HD + oct * 8;
            *reinterpret_cast<uint4*>(t_hi + base) = o;
        }
    }
}

// ---------------------------------------------------------------------------
// Phase 3: out = t @ Wo^T + bo (fp32 out). Block-stride over 672 tiles.
// ---------------------------------------------------------------------------
#define K3_BLOCKS ((MROWS / GBM) * 4)   // 672

__device__ __forceinline__ void phase_out(char* smem, int bid, int nb,
    const u16* __restrict__ Ah, const u16* __restrict__ wo_h,
    const float* __restrict__ bias, float* __restrict__ Cout)
{
    u16 (*sAh)[GBM * GBK] = reinterpret_cast<u16(*)[GBM * GBK]>(smem);
    u16 (*sBh)[GBM * GBK] = reinterpret_cast<u16(*)[GBM * GBK]>(smem + 8192);

    const int tid  = threadIdx.x;
    const int lane = tid & 63;
    const int wave = tid >> 6;
    const int wr   = wave & 1;
    const int wc   = wave >> 1;
    const int qm   = lane & 15;
    const int quad = lane >> 4;
    const int arow = (wave << 4) + (lane >> 2);
    const int ak   = (lane & 3) * 8;

    for (int t = bid; t < K3_BLOCKS; t += nb) {
        const int m0 = (t >> 2) * GBM;
        const int n0 = (t & 3) * GBN;

        const u16* Asrc = Ah   + (size_t)(m0 + arow) * CDIM + ak;
        const u16* Bsrc = wo_h + (size_t)(n0 + arow) * CDIM + ak;

        f32x4 acc[2][2];
        #pragma unroll
        for (int i = 0; i < 2; ++i)
            #pragma unroll
            for (int j = 0; j < 2; ++j)
                acc[i][j] = (f32x4){0.f, 0.f, 0.f, 0.f};

        g2lds16(Asrc, &sAh[0][wave * 512]);
        g2lds16(Bsrc, &sBh[0][wave * 512]);
        __syncthreads();

        int cur = 0;
        for (int k0 = 0; k0 < CDIM; k0 += GBK) {
            if (k0 + GBK < CDIM) {
                g2lds16(Asrc + k0 + GBK, &sAh[cur ^ 1][wave * 512]);
                g2lds16(Bsrc + k0 + GBK, &sBh[cur ^ 1][wave * 512]);
            }

            bf16x8 fah[2], fbh[2];
            #pragma unroll
            for (int x = 0; x < 2; ++x) {
                const int rm = wr * 32 + x * 16 + qm;
                const int rn = wc * 32 + x * 16 + qm;
                fah[x] = *reinterpret_cast<const bf16x8*>(&sAh[cur][rm * GBK + quad * 8]);
                fbh[x] = *reinterpret_cast<const bf16x8*>(&sBh[cur][rn * GBK + quad * 8]);
            }
            #pragma unroll
            for (int mi = 0; mi < 2; ++mi)
                #pragma unroll
                for (int ni = 0; ni < 2; ++ni)
                    acc[mi][ni] = __builtin_amdgcn_mfma_f32_16x16x32_bf16(
                        fah[mi], fbh[ni], acc[mi][ni], 0, 0, 0);
            __syncthreads();
            cur ^= 1;
        }

        #pragma unroll
        for (int mi = 0; mi < 2; ++mi) {
            #pragma unroll
            for (int ni = 0; ni < 2; ++ni) {
                const int n = n0 + wc * 32 + ni * 16 + qm;
                const float bn = bias[n];
                #pragma unroll
                for (int r = 0; r < 4; ++r) {
                    const int m = m0 + wr * 32 + mi * 16 + quad * 4 + r;
                    Cout[(size_t)m * CDIM + n] = acc[mi][ni][r] + bn;
                }
            }
        }
    }
}

// ---------------------------------------------------------------------------
// Fused single-dispatch kernel: prep -> vqa -> msda -> out with grid barriers.
// __launch_bounds__(256,4): 4 waves/EU => 4 blocks/CU floor; 24 KB LDS => 6.
// ---------------------------------------------------------------------------
__global__ __launch_bounds__(256, 4) void fused_all(
    const float* __restrict__ value, const float* __restrict__ query,
    const float* __restrict__ Wv, const float* __restrict__ Woff,
    const float* __restrict__ Wa, const float* __restrict__ Wo,
    const float* __restrict__ bv, const float* __restrict__ boff,
    const float* __restrict__ ba, const float* __restrict__ bo,
    const float* __restrict__ refp,
    u16* val_hi, u16* val_lo, u16* q_hi,
    u16* wv_h, u16* wqa_h, u16* wo_h,
    u16* v_bf16, u16* ws_off, u16* ws_a, u16* t_hi,
    float* out, unsigned* bars)
{
    __shared__ __align__(16) char smem[24576];
    const int bid = blockIdx.x;
    const int nb  = gridDim.x;

    phase_prep(bid, nb, value, query, Wv, Woff, Wa, Wo,
               val_hi, val_lo, q_hi, wv_h, wqa_h, wo_h);
    grid_barrier(bars + 0, nb);

    phase_vqa(smem, bid, nb, val_hi, val_lo, q_hi, wv_h, wqa_h,
              bv, boff, ba, v_bf16, ws_off, ws_a);
    grid_barrier(bars + 32, nb);

    phase_msda(smem, bid, nb, ws_off, ws_a, refp, v_bf16, t_hi);
    grid_barrier(bars + 64, nb);

    phase_out(smem, bid, nb, t_hi, wo_h, bo, out);
}

// ---------------------------------------------------------------------------
// Fallback thin kernels (used only if the occupancy query fails).
// ---------------------------------------------------------------------------
__global__ __launch_bounds__(256) void prep_k(
    const float* value, const float* query, const float* Wv,
    const float* Woff, const float* Wa, const float* Wo,
    u16* val_hi, u16* val_lo, u16* q_hi, u16* wv_h, u16* wqa_h, u16* wo_h)
{
    phase_prep(blockIdx.x, gridDim.x, value, query, Wv, Woff, Wa, Wo,
               val_hi, val_lo, q_hi, wv_h, wqa_h, wo_h);
}

__global__ __launch_bounds__(256) void vqa_k(
    const u16* val_hi, const u16* val_lo, const u16* q_hi,
    const u16* wv_h, const u16* wqa_h,
    const float* bv, const float* boff, const float* ba,
    u16* vOut, u16* offOut, u16* aOut)
{
    __shared__ __align__(16) char smem[24576];
    phase_vqa(smem, blockIdx.x, gridDim.x, val_hi, val_lo, q_hi, wv_h, wqa_h,
              bv, boff, ba, vOut, offOut, aOut);
}

__global__ __launch_bounds__(256) void msda_k(
    const u16* off, const u16* alog, const float* refp, const u16* v, u16* t_hi)
{
    __shared__ __align__(16) char smem[13824];
    phase_msda(smem, blockIdx.x, gridDim.x, off, alog, refp, v, t_hi);
}

__global__ __launch_bounds__(256) void out_k(
    const u16* Ah, const u16* wo_h, const float* bias, float* Cout)
{
    __shared__ __align__(16) char smem[16384];
    phase_out(smem, blockIdx.x, gridDim.x, Ah, wo_h, bias, Cout);
}

// ---------------------------------------------------------------------------
// Launch: 1 memset node + 1 fused dispatch (fallback: 4 dispatches).
// ---------------------------------------------------------------------------
extern "C" void kernel_launch(void* const* d_in, const int* in_sizes, int n_in,
                              void* d_out, int out_size, void* d_ws, size_t ws_size,
                              hipStream_t stream)
{
    const float* query = (const float*)d_in[0];   // (B,NQ,C)
    const float* refp  = (const float*)d_in[1];   // (B,NQ,2)
    const float* value = (const float*)d_in[2];   // (B,NV,C)
    const float* Wv    = (const float*)d_in[3];   // (C,C)
    const float* bv    = (const float*)d_in[4];
    const float* Woff  = (const float*)d_in[5];   // (192,C)
    const float* boff  = (const float*)d_in[6];
    const float* Wa    = (const float*)d_in[7];   // (96,C)
    const float* ba    = (const float*)d_in[8];
    const float* Wo    = (const float*)d_in[9];   // (C,C)
    const float* bo    = (const float*)d_in[10];
    float* out = (float*)d_out;

    // ---- workspace layout ----
    char* w = (char*)d_ws;
    const size_t SZ_T = (size_t)MROWS * CDIM * 2;     // 5.5 MB
    u16* v_bf16 = (u16*)(w);
    u16* t_hi   = (u16*)(w + 1 * SZ_T);
    u16* ws_off = (u16*)(w + 2 * SZ_T);               // (MROWS,192) bf16
    u16* ws_a   = (u16*)(w + 2 * SZ_T + (size_t)MROWS * NOFF * 2);
    char* w2    = w + 2 * SZ_T + (size_t)MROWS * NQA * 2;
    u16* val_hi = (u16*)(w2);
    u16* val_lo = (u16*)(w2 + 1 * SZ_T);
    u16* q_hi   = (u16*)(w2 + 2 * SZ_T);
    u16* wv_h   = (u16*)(w2 + 3 * SZ_T);
    u16* wqa_h  = (u16*)(w2 + 3 * SZ_T + (size_t)CDIM * CDIM * 2);
    u16* wo_h   = (u16*)(w2 + 3 * SZ_T + (size_t)CDIM * CDIM * 2
                              + (size_t)NQAP * CDIM * 2);
    unsigned* bars = (unsigned*)(w2 + 3 * SZ_T + (size_t)CDIM * CDIM * 2
                              + (size_t)NQAP * CDIM * 2
                              + (size_t)CDIM * CDIM * 2);

    const dim3 blk(256);

    int mb = 0;
    hipError_t qe = hipOccupancyMaxActiveBlocksPerMultiprocessor(&mb, fused_all, 256, 0);

    if (qe == hipSuccess && mb >= 1) {
        int grid = mb * 256;          // guaranteed co-resident on 256 CUs
        if (grid > 1024) grid = 1024; // cap barrier contention
        hipMemsetAsync(bars, 0, 512, stream);   // zero barrier counters each replay
        fused_all<<<dim3(grid), blk, 0, stream>>>(
            value, query, Wv, Woff, Wa, Wo, bv, boff, ba, bo, refp,
            val_hi, val_lo, q_hi, wv_h, wqa_h, wo_h,
            v_bf16, ws_off, ws_a, t_hi, out, bars);
    } else {
        // fallback: proven 4-dispatch pipeline
        prep_k<<<dim3(PREP_BLOCKS), blk, 0, stream>>>(
            value, query, Wv, Woff, Wa, Wo,
            val_hi, val_lo, q_hi, wv_h, wqa_h, wo_h);
        vqa_k<<<dim3(K1_BLOCKS), blk, 0, stream>>>(
            val_hi, val_lo, q_hi, wv_h, wqa_h, bv, boff, ba,
            v_bf16, ws_off, ws_a);
        msda_k<<<dim3(MROWS / 4), blk, 0, stream>>>(
            ws_off, ws_a, refp, v_bf16, t_hi);
        out_k<<<dim3(K3_BLOCKS), blk, 0, stream>>>(
            t_hi, wo_h, bo, out);
    }
}

// Round 4
// 133.872 us; speedup vs baseline: 2.2530x; 2.2530x over previous
//
#include <hip/hip_runtime.h>
#include <hip/hip_bf16.h>
#include <cmath>

// Problem constants (from reference)
#define BATCH   2
#define NQ      5376
#define NV      5376
#define CDIM    256
#define HEADS   8
#define HD      32
#define LEVELS  3
#define POINTS  4
#define TP      96      // HEADS*LEVELS*POINTS
#define MROWS   (BATCH*NQ)   // 10752
#define NOFF    (TP*2)       // 192
#define NQA     (NOFF+TP)    // 288 merged off||a columns
#define NQAP    320          // padded rows of merged qa weight (zeros 288..319)

typedef __attribute__((ext_vector_type(8))) short bf16x8;
typedef __attribute__((ext_vector_type(4))) float f32x4;
typedef unsigned short u16;
typedef unsigned int   u32;

#define AS1 __attribute__((address_space(1)))
#define AS3 __attribute__((address_space(3)))

__device__ __forceinline__ void g2lds16(const void* g, void* l) {
    // async global->LDS, 16B per lane; LDS dest = wave-uniform base + lane*16
    __builtin_amdgcn_global_load_lds((const AS1 void*)g, (AS3 void*)l, 16, 0, 0);
}

__device__ __forceinline__ u16 bf_of(float f) {
    union { __hip_bfloat16 h; u16 s; } u;
    u.h = __float2bfloat16(f);
    return u.s;
}
__device__ __forceinline__ float bf_back(u16 s) {
    return __uint_as_float((u32)s << 16);
}

__device__ __forceinline__ ushort4 cvt_hi(float4 v) {
    ushort4 h;
    h.x = bf_of(v.x); h.y = bf_of(v.y); h.z = bf_of(v.z); h.w = bf_of(v.w);
    return h;
}
__device__ __forceinline__ ushort4 cvt_lo(float4 v, ushort4 h) {
    ushort4 l;
    l.x = bf_of(v.x - bf_back(h.x));
    l.y = bf_of(v.y - bf_back(h.y));
    l.z = bf_of(v.z - bf_back(h.z));
    l.w = bf_of(v.w - bf_back(h.w));
    return l;
}

// ---------------------------------------------------------------------------
// Kernel 0: one-shot conversion pass (memory-bound, ~40 MB).
//   value -> val_hi, val_lo (bf16 RTNE + residual)
//   query -> q_hi ; Wv -> wv_h ; Woff||Wa -> wqa_h (320 rows, zero-padded);
//   Wo -> wo_h
// ---------------------------------------------------------------------------
#define NVAL8  344064   // 2*5376*256/8
#define NQRY8  344064
#define NWV8   8192     // 256*256/8
#define NWOFF8 6144     // 192*256/8
#define NWA8   3072     // 96*256/8
#define NWO8   8192
#define NPAD8  1024     // 32*256/8
#define PREP_BLOCKS 2792  // (sum of the above)/256 exactly
__global__ __launch_bounds__(256) void prep_kernel(
    const float* __restrict__ value, const float* __restrict__ query,
    const float* __restrict__ Wv, const float* __restrict__ Woff,
    const float* __restrict__ Wa, const float* __restrict__ Wo,
    u16* __restrict__ val_hi, u16* __restrict__ val_lo,
    u16* __restrict__ q_hi, u16* __restrict__ wv_h,
    u16* __restrict__ wqa_h, u16* __restrict__ wo_h)
{
    int r = blockIdx.x * 256 + threadIdx.x;

    if (r < NVAL8) {
        const float4 a0 = *reinterpret_cast<const float4*>(value + (size_t)r * 8);
        const float4 a1 = *reinterpret_cast<const float4*>(value + (size_t)r * 8 + 4);
        const ushort4 h0 = cvt_hi(a0), h1 = cvt_hi(a1);
        *reinterpret_cast<ushort4*>(val_hi + (size_t)r * 8)     = h0;
        *reinterpret_cast<ushort4*>(val_hi + (size_t)r * 8 + 4) = h1;
        *reinterpret_cast<ushort4*>(val_lo + (size_t)r * 8)     = cvt_lo(a0, h0);
        *reinterpret_cast<ushort4*>(val_lo + (size_t)r * 8 + 4) = cvt_lo(a1, h1);
        return;
    }
    r -= NVAL8;
    if (r < NQRY8) {
        const float4 a0 = *reinterpret_cast<const float4*>(query + (size_t)r * 8);
        const float4 a1 = *reinterpret_cast<const float4*>(query + (size_t)r * 8 + 4);
        *reinterpret_cast<ushort4*>(q_hi + (size_t)r * 8)     = cvt_hi(a0);
        *reinterpret_cast<ushort4*>(q_hi + (size_t)r * 8 + 4) = cvt_hi(a1);
        return;
    }
    r -= NQRY8;
    if (r < NWV8) {
        const float4 a0 = *reinterpret_cast<const float4*>(Wv + (size_t)r * 8);
        const float4 a1 = *reinterpret_cast<const float4*>(Wv + (size_t)r * 8 + 4);
        *reinterpret_cast<ushort4*>(wv_h + (size_t)r * 8)     = cvt_hi(a0);
        *reinterpret_cast<ushort4*>(wv_h + (size_t)r * 8 + 4) = cvt_hi(a1);
        return;
    }
    r -= NWV8;
    if (r < NWOFF8) {
        const float4 a0 = *reinterpret_cast<const float4*>(Woff + (size_t)r * 8);
        const float4 a1 = *reinterpret_cast<const float4*>(Woff + (size_t)r * 8 + 4);
        *reinterpret_cast<ushort4*>(wqa_h + (size_t)r * 8)     = cvt_hi(a0);
        *reinterpret_cast<ushort4*>(wqa_h + (size_t)r * 8 + 4) = cvt_hi(a1);
        return;
    }
    r -= NWOFF8;
    if (r < NWA8) {
        const float4 a0 = *reinterpret_cast<const float4*>(Wa + (size_t)r * 8);
        const float4 a1 = *reinterpret_cast<const float4*>(Wa + (size_t)r * 8 + 4);
        u16* dst = wqa_h + (size_t)NOFF * CDIM;
        *reinterpret_cast<ushort4*>(dst + (size_t)r * 8)     = cvt_hi(a0);
        *reinterpret_cast<ushort4*>(dst + (size_t)r * 8 + 4) = cvt_hi(a1);
        return;
    }
    r -= NWA8;
    if (r < NWO8) {
        const float4 a0 = *reinterpret_cast<const float4*>(Wo + (size_t)r * 8);
        const float4 a1 = *reinterpret_cast<const float4*>(Wo + (size_t)r * 8 + 4);
        *reinterpret_cast<ushort4*>(wo_h + (size_t)r * 8)     = cvt_hi(a0);
        *reinterpret_cast<ushort4*>(wo_h + (size_t)r * 8 + 4) = cvt_hi(a1);
        return;
    }
    r -= NWO8;
    // zero padding rows 288..319 of wqa_h
    const ushort4 z = {0, 0, 0, 0};
    u16* dst = wqa_h + (size_t)NQA * CDIM;
    *reinterpret_cast<ushort4*>(dst + (size_t)r * 8)     = z;
    *reinterpret_cast<ushort4*>(dst + (size_t)r * 8 + 4) = z;
}

// ---------------------------------------------------------------------------
// GEMM tiles: 64x64x32, 256 threads = 4 waves (2x2 of 32x32 wave tiles).
// Pure bf16, global_load_lds staging, 2-phase dbuf, XCD-chunk swizzle.
//
// LDS chunk-XOR swizzle (T2, rule 21 both-sides-or-neither):
//   LDS[r][chunk c] = G[r][chunk c ^ (r&3)]   (chunks = 16B = 8 bf16)
//   write side: g2lds dest stays LINEAR; the global SOURCE chunk per staging
//     lane l is (l&3) ^ ((l>>2)&3)  (lane l writes local row l>>2, slot l&3)
//   read side: fragment wanting G[rm][quad] reads slot quad ^ (rm&3).
// This turns the 8-way ds_read_b128 bank conflict (16 lanes, 64B row stride,
// fixed 16B column -> 2 banks) into 2 lanes/bank = free.
// ---------------------------------------------------------------------------
#define GBM 64
#define GBN 64
#define GBK 32

#define VBLOCKS (168 * 4)       // 672 v-path blocks
#define K1_BLOCKS (VBLOCKS + 168 * 5)   // 1512, %8==0
#define K1_CPX (K1_BLOCKS / 8)          // 189

__global__ __launch_bounds__(256) void gemm_vqa_kernel(
    const u16* __restrict__ val_hi, const u16* __restrict__ val_lo,
    const u16* __restrict__ q_hi,
    const u16* __restrict__ wv_h, const u16* __restrict__ wqa_h,
    const float* __restrict__ bv, const float* __restrict__ boff,
    const float* __restrict__ ba,
    u16* __restrict__ vOut, u16* __restrict__ offOut, u16* __restrict__ aOut)
{
    __shared__ __align__(16) u16 sAh[2][GBM * GBK];   // 4 KB each buffer
    __shared__ __align__(16) u16 sAl[2][GBM * GBK];
    __shared__ __align__(16) u16 sBh[2][GBM * GBK];

    const int bid0 = blockIdx.x;
    const int bid = (bid0 & 7) * K1_CPX + (bid0 >> 3);

    const bool vpath = bid < VBLOCKS;
    int m0, n0;
    if (vpath) { m0 = (bid >> 2) * GBM;          n0 = (bid & 3) * GBM; }
    else       { const int b2 = bid - VBLOCKS;
                 m0 = (b2 / 5) * GBM;            n0 = (b2 % 5) * GBM; }

    const int tid  = threadIdx.x;
    const int lane = tid & 63;
    const int wave = tid >> 6;
    const int wr   = wave & 1;
    const int wc   = wave >> 1;
    const int qm   = lane & 15;
    const int quad = lane >> 4;

    // staging: lane l -> local row l>>2 (of wave's 16 rows), LDS slot l&3;
    // global source chunk pre-swizzled so LDS content is chunk-XOR'd.
    const int arow = (wave << 4) + (lane >> 2);
    const int ak   = (((lane & 3) ^ ((lane >> 2) & 3)) * 8);

    const u16* Asrc_h = (vpath ? val_hi : q_hi) + (size_t)(m0 + arow) * CDIM + ak;
    const u16* Asrc_l = val_lo + (size_t)(m0 + arow) * CDIM + ak;   // vpath only
    const u16* Bsrc   = (vpath ? wv_h : wqa_h) + (size_t)(n0 + arow) * CDIM + ak;

    f32x4 acc[2][2];
    #pragma unroll
    for (int i = 0; i < 2; ++i)
        #pragma unroll
        for (int j = 0; j < 2; ++j)
            acc[i][j] = (f32x4){0.f, 0.f, 0.f, 0.f};

    // prologue: stage tile 0
    {
        g2lds16(Asrc_h, &sAh[0][wave * 512]);
        if (vpath) g2lds16(Asrc_l, &sAl[0][wave * 512]);
        g2lds16(Bsrc, &sBh[0][wave * 512]);
    }
    __syncthreads();

    int cur = 0;
    for (int k0 = 0; k0 < CDIM; k0 += GBK) {
        // issue next tile's loads before computing current (2-phase dbuf)
        if (k0 + GBK < CDIM) {
            g2lds16(Asrc_h + k0 + GBK, &sAh[cur ^ 1][wave * 512]);
            if (vpath) g2lds16(Asrc_l + k0 + GBK, &sAl[cur ^ 1][wave * 512]);
            g2lds16(Bsrc + k0 + GBK, &sBh[cur ^ 1][wave * 512]);
        }

        bf16x8 fah[2], fal[2], fbh[2];
        #pragma unroll
        for (int x = 0; x < 2; ++x) {
            const int rm = wr * 32 + x * 16 + qm;
            const int rn = wc * 32 + x * 16 + qm;
            const int ca = (quad ^ (rm & 3)) * 8;   // swizzled read slot
            const int cb = (quad ^ (rn & 3)) * 8;
            fah[x] = *reinterpret_cast<const bf16x8*>(&sAh[cur][rm * GBK + ca]);
            fbh[x] = *reinterpret_cast<const bf16x8*>(&sBh[cur][rn * GBK + cb]);
            if (vpath)
                fal[x] = *reinterpret_cast<const bf16x8*>(&sAl[cur][rm * GBK + ca]);
        }
        #pragma unroll
        for (int mi = 0; mi < 2; ++mi)
            #pragma unroll
            for (int ni = 0; ni < 2; ++ni) {
                acc[mi][ni] = __builtin_amdgcn_mfma_f32_16x16x32_bf16(
                    fah[mi], fbh[ni], acc[mi][ni], 0, 0, 0);
                if (vpath)
                    acc[mi][ni] = __builtin_amdgcn_mfma_f32_16x16x32_bf16(
                        fal[mi], fbh[ni], acc[mi][ni], 0, 0, 0);
            }
        __syncthreads();   // drains next-tile g2lds (vmcnt) + protects buffers
        cur ^= 1;
    }

    // epilogue: C/D layout col = lane&15 (n), row = quad*4 + reg (m)
    #pragma unroll
    for (int mi = 0; mi < 2; ++mi) {
        #pragma unroll
        for (int ni = 0; ni < 2; ++ni) {
            const int n = n0 + wc * 32 + ni * 16 + qm;
            if (vpath) {
                const float bn = bv[n];
                #pragma unroll
                for (int r = 0; r < 4; ++r) {
                    const int m = m0 + wr * 32 + mi * 16 + quad * 4 + r;
                    const float val = acc[mi][ni][r] + bn;
                    // head-major (B, HEADS, NV, HD)
                    const int b = m / NV, rr = m - b * NV;
                    const int h = n >> 5, c = n & 31;
                    vOut[(((size_t)b * HEADS + h) * NV + rr) * HD + c] = bf_of(val);
                }
            } else {
                if (n >= NQA) continue;
                const float bn = (n < NOFF) ? boff[n] : ba[n - NOFF];
                #pragma unroll
                for (int r = 0; r < 4; ++r) {
                    const int m = m0 + wr * 32 + mi * 16 + quad * 4 + r;
                    const float val = acc[mi][ni][r] + bn;
                    if (n < NOFF)
                        offOut[(size_t)m * NOFF + n] = bf_of(val);
                    else
                        aOut[(size_t)m * TP + (n - NOFF)] = bf_of(val);
                }
            }
        }
    }
}

// --- kernel 3: out = t @ Wo^T + bo (fp32 out). Same swizzle as k1.
#define K3_BLOCKS ((MROWS / GBM) * 4)   // 672, %8==0
#define K3_CPX (K3_BLOCKS / 8)          // 84

__global__ __launch_bounds__(256) void gemm_out_kernel(
    const u16* __restrict__ Ah, const u16* __restrict__ wo_h,
    const float* __restrict__ bias, float* __restrict__ Cout)
{
    __shared__ __align__(16) u16 sAh[2][GBM * GBK];
    __shared__ __align__(16) u16 sBh[2][GBM * GBK];

    const int bid0 = blockIdx.x;
    const int bid = (bid0 & 7) * K3_CPX + (bid0 >> 3);
    const int m0 = (bid >> 2) * GBM;
    const int n0 = (bid & 3) * GBN;

    const int tid  = threadIdx.x;
    const int lane = tid & 63;
    const int wave = tid >> 6;
    const int wr   = wave & 1;
    const int wc   = wave >> 1;
    const int qm   = lane & 15;
    const int quad = lane >> 4;

    const int arow = (wave << 4) + (lane >> 2);
    const int ak   = (((lane & 3) ^ ((lane >> 2) & 3)) * 8);

    const u16* Asrc = Ah   + (size_t)(m0 + arow) * CDIM + ak;
    const u16* Bsrc = wo_h + (size_t)(n0 + arow) * CDIM + ak;

    f32x4 acc[2][2];
    #pragma unroll
    for (int i = 0; i < 2; ++i)
        #pragma unroll
        for (int j = 0; j < 2; ++j)
            acc[i][j] = (f32x4){0.f, 0.f, 0.f, 0.f};

    g2lds16(Asrc, &sAh[0][wave * 512]);
    g2lds16(Bsrc, &sBh[0][wave * 512]);
    __syncthreads();

    int cur = 0;
    for (int k0 = 0; k0 < CDIM; k0 += GBK) {
        if (k0 + GBK < CDIM) {
            g2lds16(Asrc + k0 + GBK, &sAh[cur ^ 1][wave * 512]);
            g2lds16(Bsrc + k0 + GBK, &sBh[cur ^ 1][wave * 512]);
        }

        bf16x8 fah[2], fbh[2];
        #pragma unroll
        for (int x = 0; x < 2; ++x) {
            const int rm = wr * 32 + x * 16 + qm;
            const int rn = wc * 32 + x * 16 + qm;
            const int ca = (quad ^ (rm & 3)) * 8;
            const int cb = (quad ^ (rn & 3)) * 8;
            fah[x] = *reinterpret_cast<const bf16x8*>(&sAh[cur][rm * GBK + ca]);
            fbh[x] = *reinterpret_cast<const bf16x8*>(&sBh[cur][rn * GBK + cb]);
        }
        #pragma unroll
        for (int mi = 0; mi < 2; ++mi)
            #pragma unroll
            for (int ni = 0; ni < 2; ++ni)
                acc[mi][ni] = __builtin_amdgcn_mfma_f32_16x16x32_bf16(
                    fah[mi], fbh[ni], acc[mi][ni], 0, 0, 0);
        __syncthreads();
        cur ^= 1;
    }

    #pragma unroll
    for (int mi = 0; mi < 2; ++mi) {
        #pragma unroll
        for (int ni = 0; ni < 2; ++ni) {
            const int n = n0 + wc * 32 + ni * 16 + qm;
            const float bn = bias[n];
            #pragma unroll
            for (int r = 0; r < 4; ++r) {
                const int m = m0 + wr * 32 + mi * 16 + quad * 4 + r;
                Cout[(size_t)m * CDIM + n] = acc[mi][ni][r] + bn;
            }
        }
    }
}

// ---------------------------------------------------------------------------
// MSDA core (unchanged, proven): 4 queries/block (256 threads),
// 64 threads per query = 8 heads x 4 channel-octets x 2 tap-replicas.
// ---------------------------------------------------------------------------
__global__ __launch_bounds__(256) void msda_core_kernel(
    const u16* __restrict__ off,    // (B*NQ, 192) bf16
    const u16* __restrict__ alog,   // (B*NQ, 96) bf16
    const float* __restrict__ refp, // (B*NQ, 2)
    const u16*   __restrict__ v,    // (B, HEADS, NV, HD) bf16
    u16* __restrict__ t_hi)         // (B*NQ, 256) bf16
{
    const int tid = threadIdx.x;
    const int bq0 = blockIdx.x * 4;

    __shared__ float s_w[4][TP];
    __shared__ int   s_idx[4][TP][4];   // spatial*64 byte offsets in head plane
    __shared__ float s_twt[4][TP][4];

    // logits for 4 queries (384 values)
    #pragma unroll
    for (int base = 0; base < 4 * TP; base += 256) {
        const int idx = base + tid;
        if (idx < 4 * TP) {
            const int q = idx / TP, j = idx - q * TP;
            s_w[q][j] = bf_back(alog[(size_t)(bq0 + q) * TP + j]);
        }
    }
    __syncthreads();

    // 32 softmaxes (4 queries x 8 heads)
    if (tid < 32) {
        const int q = tid >> 3, h = tid & 7;
        float mx = -1e30f;
        #pragma unroll
        for (int i = 0; i < 12; ++i) mx = fmaxf(mx, s_w[q][h * 12 + i]);
        float e[12];
        float sum = 0.f;
        #pragma unroll
        for (int i = 0; i < 12; ++i) {
            e[i] = expf(s_w[q][h * 12 + i] - mx);
            sum += e[i];
        }
        const float inv = 1.f / sum;
        #pragma unroll
        for (int i = 0; i < 12; ++i) s_w[q][h * 12 + i] = e[i] * inv;
    }
    __syncthreads();

    // taps for 4 queries (384 taps)
    #pragma unroll
    for (int base = 0; base < 4 * TP; base += 256) {
        const int idx = base + tid;
        if (idx < 4 * TP) {
            const int q = idx / TP, j = idx - q * TP;
            const int bq = bq0 + q;
            const int jj = j % 12;
            const int l  = jj >> 2;
            const int Wl    = (l == 0) ? 64 : (l == 1) ? 32 : 16;
            const int start = (l == 0) ? 0 : (l == 1) ? 4096 : 5120;

            const float refx = refp[(size_t)bq * 2 + 0];
            const float refy = refp[(size_t)bq * 2 + 1];
            const float ox = bf_back(off[(size_t)bq * NOFF + j * 2 + 0]);
            const float oy = bf_back(off[(size_t)bq * NOFF + j * 2 + 1]);
            const float lx = fminf(fmaxf(refx + ox, 0.f), 1.f) * (float)Wl - 0.5f;
            const float ly = fminf(fmaxf(refy + oy, 0.f), 1.f) * (float)Wl - 0.5f;
            const float fx0 = floorf(lx), fy0 = floorf(ly);
            const int   x0  = (int)fx0,   y0  = (int)fy0;
            const float wx1 = lx - fx0,   wy1 = ly - fy0;
            const float wx0 = 1.f - wx1,  wy0 = 1.f - wy1;
            const float aw  = s_w[q][j];

            #pragma unroll
            for (int k = 0; k < 4; ++k) {
                const int dx = k & 1, dy = k >> 1;
                const int xi = x0 + dx, yi = y0 + dy;
                const bool ok = (xi >= 0) & (xi < Wl) & (yi >= 0) & (yi < Wl);
                const int xc = min(max(xi, 0), Wl - 1);
                const int yc = min(max(yi, 0), Wl - 1);
                s_idx[q][j][k] = (start + yc * Wl + xc) * (HD * 2);  // 64 B rows
                const float wxy = (dx ? wx1 : wx0) * (dy ? wy1 : wy0);
                s_twt[q][j][k] = ok ? aw * wxy : 0.f;
            }
        }
    }
    __syncthreads();

    // gather: 64 threads per query
    const int qsel = tid >> 6;          // 0..3 (one wave per query)
    const int ht   = tid & 63;
    const int h    = ht >> 3;           // 0..7
    const int sub  = ht & 7;
    const int oct  = sub & 3;           // channels 8*oct .. 8*oct+7
    const int rep  = sub >> 2;          // replica 0/1 -> taps [6r, 6r+6)
    const int bq   = bq0 + qsel;
    const int b    = bq / NQ;
    const char* vb = (const char*)v + (((size_t)b * HEADS + h) * NV) * (HD * 2) + oct * 16;

    float acc[8] = {};
    #pragma unroll
    for (int g = 0; g < 3; ++g) {        // 3 groups x 2 taps x 4 corners = 8 loads
        uint4 raw[8];
        float wt[8];
        #pragma unroll
        for (int pp = 0; pp < 2; ++pp) {
            const int j = h * 12 + rep * 6 + g * 2 + pp;
            const int4   ix = *reinterpret_cast<const int4*>(&s_idx[qsel][j][0]);
            const float4 tw = *reinterpret_cast<const float4*>(&s_twt[qsel][j][0]);
            raw[pp * 4 + 0] = *reinterpret_cast<const uint4*>(vb + ix.x);
            raw[pp * 4 + 1] = *reinterpret_cast<const uint4*>(vb + ix.y);
            raw[pp * 4 + 2] = *reinterpret_cast<const uint4*>(vb + ix.z);
            raw[pp * 4 + 3] = *reinterpret_cast<const uint4*>(vb + ix.w);
            wt[pp * 4 + 0] = tw.x; wt[pp * 4 + 1] = tw.y;
            wt[pp * 4 + 2] = tw.z; wt[pp * 4 + 3] = tw.w;
        }
        #pragma unroll
        for (int k = 0; k < 8; ++k) {
            acc[0] += wt[k] * __uint_as_float(raw[k].x << 16);
            acc[1] += wt[k] * __uint_as_float(raw[k].x & 0xffff0000u);
            acc[2] += wt[k] * __uint_as_float(raw[k].y << 16);
            acc[3] += wt[k] * __uint_as_float(raw[k].y & 0xffff0000u);
            acc[4] += wt[k] * __uint_as_float(raw[k].z << 16);
            acc[5] += wt[k] * __uint_as_float(raw[k].z & 0xffff0000u);
            acc[6] += wt[k] * __uint_as_float(raw[k].w << 16);
            acc[7] += wt[k] * __uint_as_float(raw[k].w & 0xffff0000u);
        }
    }

    // combine the two tap-replicas (lanes differ in bit 2)
    #pragma unroll
    for (int c = 0; c < 8; ++c)
        acc[c] += __shfl_xor(acc[c], 4);

    if (rep == 0) {
        uint4 o;
        o.x = (u32)bf_of(acc[0]) | ((u32)bf_of(acc[1]) << 16);
        o.y = (u32)bf_of(acc[2]) | ((u32)bf_of(acc[3]) << 16);
        o.z = (u32)bf_of(acc[4]) | ((u32)bf_of(acc[5]) << 16);
        o.w = (u32)bf_of(acc[6]) | ((u32)bf_of(acc[7]) << 16);
        const size_t base = (size_t)bq * CDIM + h * HD + oct * 8;
        *reinterpret_cast<uint4*>(t_hi + base) = o;
    }
}

// ---------------------------------------------------------------------------
// Launch: 4 dispatches total.
// ---------------------------------------------------------------------------
extern "C" void kernel_launch(void* const* d_in, const int* in_sizes, int n_in,
                              void* d_out, int out_size, void* d_ws, size_t ws_size,
                              hipStream_t stream)
{
    const float* query = (const float*)d_in[0];   // (B,NQ,C)
    const float* refp  = (const float*)d_in[1];   // (B,NQ,2)
    const float* value = (const float*)d_in[2];   // (B,NV,C)
    const float* Wv    = (const float*)d_in[3];   // (C,C)
    const float* bv    = (const float*)d_in[4];
    const float* Woff  = (const float*)d_in[5];   // (192,C)
    const float* boff  = (const float*)d_in[6];
    const float* Wa    = (const float*)d_in[7];   // (96,C)
    const float* ba    = (const float*)d_in[8];
    const float* Wo    = (const float*)d_in[9];   // (C,C)
    const float* bo    = (const float*)d_in[10];
    float* out = (float*)d_out;

    // ---- workspace layout (all bf16) ----
    char* w = (char*)d_ws;
    const size_t SZ_T = (size_t)MROWS * CDIM * 2;     // 5.5 MB
    u16* v_bf16 = (u16*)(w);                          // head-major gather source
    u16* t_hi   = (u16*)(w + 1 * SZ_T);
    u16* ws_off = (u16*)(w + 2 * SZ_T);               // (MROWS,192) bf16
    u16* ws_a   = (u16*)(w + 2 * SZ_T + (size_t)MROWS * NOFF * 2);
    char* w2    = w + 2 * SZ_T + (size_t)MROWS * NQA * 2;
    u16* val_hi = (u16*)(w2);
    u16* val_lo = (u16*)(w2 + 1 * SZ_T);
    u16* q_hi   = (u16*)(w2 + 2 * SZ_T);
    u16* wv_h   = (u16*)(w2 + 3 * SZ_T);
    u16* wqa_h  = (u16*)(w2 + 3 * SZ_T + (size_t)CDIM * CDIM * 2);
    u16* wo_h   = (u16*)(w2 + 3 * SZ_T + (size_t)CDIM * CDIM * 2
                              + (size_t)NQAP * CDIM * 2);

    const dim3 blk(256);

    // 0) one-shot bf16 conversion of all GEMM operands
    prep_kernel<<<dim3(PREP_BLOCKS), blk, 0, stream>>>(
        value, query, Wv, Woff, Wa, Wo,
        val_hi, val_lo, q_hi, wv_h, wqa_h, wo_h);

    // 1) v-GEMM (bf16 head-major out) + qa-GEMM (bf16 off||a out), bf16 in
    gemm_vqa_kernel<<<dim3(K1_BLOCKS), blk, 0, stream>>>(
        val_hi, val_lo, q_hi, wv_h, wqa_h,
        bv, boff, ba, v_bf16, ws_off, ws_a);

    // 2) sampling core -> t_hi (bf16)
    msda_core_kernel<<<dim3(MROWS / 4), blk, 0, stream>>>(
        ws_off, ws_a, refp, v_bf16, t_hi);

    // 3) out = t @ Wo^T + bo (fp32 out)
    gemm_out_kernel<<<dim3(K3_BLOCKS), blk, 0, stream>>>(
        t_hi, wo_h, bo, out);
}